// Round 4
// baseline (1114.401 us; speedup 1.0000x reference)
//
#include <hip/hip_runtime.h>
#include <cstddef>
#include <cstdint>

// ---------------- problem constants ----------------
#define T_TOK 4096      // BATCH*SEQ
#define DIM   1024
#define HID   2816
#define NE    8
#define TOPK  2
#define CAP   9216      // 72 row-tiles * 128 (8192 assignments + per-expert 128-align pad)
#define NRT   72        // CAP / BM

#define BM 128
#define BN 64
#define BK 32

// ---------------- workspace layout (bytes) ----------------
#define WS_COUNTS  0                         // 8  int
#define WS_CURSORS 64                        // 8  int
#define WS_OFFSETS 128                       // 9  int
#define WS_TILE_E  256                       // 72 int
#define WS_SEL     1024                      // T*2 int   (32 KB)
#define WS_WTS     (WS_SEL  + T_TOK*2*4)     // T*2 float (32 KB)
#define WS_ATOK    (WS_WTS  + T_TOK*2*4)     // CAP int
#define WS_AW      (WS_ATOK + CAP*4)         // CAP float
#define WS_H       140288                    // CAP*CH float; CH chosen to fit ws_size (256B aligned)

typedef __attribute__((ext_vector_type(8))) short bf16x8;   // 8 bf16 in 4 VGPRs (guide §3)
typedef __attribute__((ext_vector_type(4))) float f32x4;    // MFMA 16x16 accumulator

// fp32 -> bf16 RNE, manual (finite data only; avoids header type issues)
__device__ __forceinline__ unsigned short f2bf(float f) {
  unsigned int u = __builtin_bit_cast(unsigned int, f);
  unsigned int r = u + 0x7FFFu + ((u >> 16) & 1u);
  return (unsigned short)(r >> 16);
}
__device__ __forceinline__ float bf2f(unsigned short s) {
  unsigned int u = ((unsigned int)s) << 16;
  return __builtin_bit_cast(float, u);
}
__device__ __forceinline__ void split2(float f, unsigned short& hi, unsigned short& lo) {
  hi = f2bf(f);
  lo = f2bf(f - bf2f(hi));
}

// LDS offset (in ushorts) of element (row,k) in frag-block-contiguous layout:
// [row>>4 block of 1KB][k>>3 slot of 256B][row&15][k&7] -> wave frag read = contiguous 1KB
__device__ __forceinline__ int fragoff(int row, int k) {
  return ((row >> 4) << 9) + ((k >> 3) << 7) + ((row & 15) << 3) + (k & 7);
}

// ---------------- gating: one wave per token (unchanged) ----------------
__global__ __launch_bounds__(256) void gate_kernel(
    const float* __restrict__ x, const float* __restrict__ gw,
    int* __restrict__ sel, float* __restrict__ wts, int* __restrict__ counts)
{
  const int wave = threadIdx.x >> 6;
  const int lane = threadIdx.x & 63;
  const int t = blockIdx.x * 4 + wave;

  const float* xr = x + (size_t)t * DIM;
  float acc[NE] = {0.f, 0.f, 0.f, 0.f, 0.f, 0.f, 0.f, 0.f};

#pragma unroll 4
  for (int j = 0; j < DIM / 64; ++j) {
    const int d = lane + 64 * j;
    const float xv = xr[d];
#pragma unroll
    for (int e = 0; e < NE; ++e) acc[e] = fmaf(xv, gw[e * DIM + d], acc[e]);
  }
#pragma unroll
  for (int m = 32; m > 0; m >>= 1) {
#pragma unroll
    for (int e = 0; e < NE; ++e) acc[e] += __shfl_xor(acc[e], m, 64);
  }

  if (lane == 0) {
    float mx = acc[0];
#pragma unroll
    for (int e = 1; e < NE; ++e) mx = fmaxf(mx, acc[e]);
    float ex[NE];
#pragma unroll
    for (int e = 0; e < NE; ++e) ex[e] = __expf(acc[e] - mx);
    int e0 = 0; float p0 = ex[0];
#pragma unroll
    for (int e = 1; e < NE; ++e) if (ex[e] > p0) { p0 = ex[e]; e0 = e; }
    int e1 = -1; float p1 = -1.f;
#pragma unroll
    for (int e = 0; e < NE; ++e) if (e != e0 && ex[e] > p1) { p1 = ex[e]; e1 = e; }
    const float inv = 1.f / (p0 + p1);   // softmax denom cancels in renorm
    sel[2 * t + 0] = e0; sel[2 * t + 1] = e1;
    wts[2 * t + 0] = p0 * inv; wts[2 * t + 1] = p1 * inv;
    atomicAdd(&counts[e0], 1);
    atomicAdd(&counts[e1], 1);
  }
}

// ---------------- offsets: 128-aligned expert regions ----------------
__global__ void offsets_kernel(const int* __restrict__ counts,
                               int* __restrict__ offsets, int* __restrict__ cursors,
                               int* __restrict__ tile_e)
{
  if (threadIdx.x == 0 && blockIdx.x == 0) {
    int off = 0;
    for (int e = 0; e < NE; ++e) {
      offsets[e] = off;
      cursors[e] = off;
      off += (counts[e] + 127) & ~127;   // 128-align: every BM=128 tile is single-expert
    }
    offsets[NE] = off;
    for (int t = 0; t < NRT; ++t) {
      const int r = t * BM;
      int ee = 0;
      while (ee < NE - 1 && r >= offsets[ee + 1]) ++ee;
      tile_e[t] = ee;                    // all-pad tiles get last expert; harmless
    }
  }
}

// ---------------- scatter assignments (unchanged) ----------------
__global__ __launch_bounds__(256) void scatter_kernel(
    const int* __restrict__ sel, const float* __restrict__ wts,
    int* __restrict__ cursors, int* __restrict__ atok, float* __restrict__ aw)
{
  const int t = blockIdx.x * 256 + threadIdx.x;
  if (t < T_TOK) {
#pragma unroll
    for (int k = 0; k < TOPK; ++k) {
      const int e = sel[2 * t + k];
      const int pos = atomicAdd(&cursors[e], 1);
      atok[pos] = t;
      aw[pos] = wts[2 * t + k];
    }
  }
}

// ---------------- GEMM1 (MFMA bf16x3): h = silu(x W1^T) * (x W3^T) ----------------
__global__ __launch_bounds__(256, 2) void gemm1_kernel(
    const float* __restrict__ x, const float* __restrict__ w1,
    const float* __restrict__ w3, const int* __restrict__ atok,
    const int* __restrict__ tile_e, float* __restrict__ h,
    int hc0, int CH)
{
  __shared__ unsigned short sAh[4096], sAl[4096];            // 128x32 hi/lo
  __shared__ unsigned short sB1h[2048], sB1l[2048];          // 64x32
  __shared__ unsigned short sB3h[2048], sB3l[2048];
  __shared__ int sToks[BM];

  const int rt = blockIdx.x, ct = blockIdx.y;
  const int row0 = rt * BM;
  const int tid = threadIdx.x;
  const int lane = tid & 63;
  const int wv = tid >> 6, wr = wv >> 1, wc = wv & 1;        // 2x2 waves; wave tile 64x32
  const int e = tile_e[rt];

  if (tid < BM) {
    const int tk = atok[row0 + tid];
    sToks[tid] = tk < 0 ? 0 : tk;      // pad rows gather token 0 (finite, never scattered)
  }
  __syncthreads();

  // staging: thread handles float4 at (srow + 32*i, c4*4) of each tile
  const int c4 = tid & 7;
  const int srow = tid >> 3;
  const float* ax[4];
  int aadr[4];
#pragma unroll
  for (int i = 0; i < 4; ++i) {
    const int r = srow + 32 * i;
    ax[i] = x + (size_t)sToks[r] * DIM + c4 * 4;
    aadr[i] = fragoff(r, c4 * 4);
  }
  const float* W1p = w1 + ((size_t)e * HID + hc0 + ct * BN) * DIM;
  const float* W3p = w3 + ((size_t)e * HID + hc0 + ct * BN) * DIM;
  const float* b1p[2]; const float* b3p[2];
  int badr[2];
#pragma unroll
  for (int i = 0; i < 2; ++i) {
    const int c = srow + 32 * i;
    b1p[i] = W1p + (size_t)c * DIM + c4 * 4;
    b3p[i] = W3p + (size_t)c * DIM + c4 * 4;
    badr[i] = fragoff(c, c4 * 4);
  }

  const f32x4 vz = {0.f, 0.f, 0.f, 0.f};
  f32x4 acc1[4][2], acc3[4][2];
#pragma unroll
  for (int i = 0; i < 4; ++i)
#pragma unroll
    for (int j = 0; j < 2; ++j) { acc1[i][j] = vz; acc3[i][j] = vz; }

  for (int kt = 0; kt < DIM / BK; ++kt) {
    const int k0 = kt * BK;
    float4 av[4], b1v[2], b3v[2];
#pragma unroll
    for (int i = 0; i < 4; ++i) av[i] = *(const float4*)(ax[i] + k0);
#pragma unroll
    for (int i = 0; i < 2; ++i) {
      b1v[i] = *(const float4*)(b1p[i] + k0);
      b3v[i] = *(const float4*)(b3p[i] + k0);
    }
    __syncthreads();                    // previous iteration's frag reads complete
#pragma unroll
    for (int i = 0; i < 4; ++i) {
      ushort4 hi, lo;
      split2(av[i].x, hi.x, lo.x); split2(av[i].y, hi.y, lo.y);
      split2(av[i].z, hi.z, lo.z); split2(av[i].w, hi.w, lo.w);
      *(ushort4*)&sAh[aadr[i]] = hi;  *(ushort4*)&sAl[aadr[i]] = lo;
    }
#pragma unroll
    for (int i = 0; i < 2; ++i) {
      ushort4 hi, lo;
      split2(b1v[i].x, hi.x, lo.x); split2(b1v[i].y, hi.y, lo.y);
      split2(b1v[i].z, hi.z, lo.z); split2(b1v[i].w, hi.w, lo.w);
      *(ushort4*)&sB1h[badr[i]] = hi; *(ushort4*)&sB1l[badr[i]] = lo;
      split2(b3v[i].x, hi.x, lo.x); split2(b3v[i].y, hi.y, lo.y);
      split2(b3v[i].z, hi.z, lo.z); split2(b3v[i].w, hi.w, lo.w);
      *(ushort4*)&sB3h[badr[i]] = hi; *(ushort4*)&sB3l[badr[i]] = lo;
    }
    __syncthreads();

    bf16x8 ah[4], al[4], g1h[2], g1l[2], g3h[2], g3l[2];
#pragma unroll
    for (int ar = 0; ar < 4; ++ar) {
      const int rb = wr * 4 + ar;
      ah[ar] = *(const bf16x8*)&sAh[rb * 512 + lane * 8];
      al[ar] = *(const bf16x8*)&sAl[rb * 512 + lane * 8];
    }
#pragma unroll
    for (int bc = 0; bc < 2; ++bc) {
      const int cb = wc * 2 + bc;
      g1h[bc] = *(const bf16x8*)&sB1h[cb * 512 + lane * 8];
      g1l[bc] = *(const bf16x8*)&sB1l[cb * 512 + lane * 8];
      g3h[bc] = *(const bf16x8*)&sB3h[cb * 512 + lane * 8];
      g3l[bc] = *(const bf16x8*)&sB3l[cb * 512 + lane * 8];
    }
#pragma unroll
    for (int ar = 0; ar < 4; ++ar)
#pragma unroll
      for (int bc = 0; bc < 2; ++bc) {
        acc1[ar][bc] = __builtin_amdgcn_mfma_f32_16x16x32_bf16(ah[ar], g1h[bc], acc1[ar][bc], 0, 0, 0);
        acc1[ar][bc] = __builtin_amdgcn_mfma_f32_16x16x32_bf16(ah[ar], g1l[bc], acc1[ar][bc], 0, 0, 0);
        acc1[ar][bc] = __builtin_amdgcn_mfma_f32_16x16x32_bf16(al[ar], g1h[bc], acc1[ar][bc], 0, 0, 0);
        acc3[ar][bc] = __builtin_amdgcn_mfma_f32_16x16x32_bf16(ah[ar], g3h[bc], acc3[ar][bc], 0, 0, 0);
        acc3[ar][bc] = __builtin_amdgcn_mfma_f32_16x16x32_bf16(ah[ar], g3l[bc], acc3[ar][bc], 0, 0, 0);
        acc3[ar][bc] = __builtin_amdgcn_mfma_f32_16x16x32_bf16(al[ar], g3h[bc], acc3[ar][bc], 0, 0, 0);
      }
  }

  // epilogue: D layout col=lane&15, row=(lane>>4)*4+reg (m89-verified)
#pragma unroll
  for (int ar = 0; ar < 4; ++ar)
#pragma unroll
    for (int bc = 0; bc < 2; ++bc)
#pragma unroll
      for (int r = 0; r < 4; ++r) {
        const int row = row0 + wr * 64 + ar * 16 + (lane >> 4) * 4 + r;
        const int col = ct * BN + wc * 32 + bc * 16 + (lane & 15);   // local within chunk
        const float g = acc1[ar][bc][r];
        const float u = acc3[ar][bc][r];
        const float s = g / (1.f + __expf(-g));
        h[(size_t)row * CH + col] = s * u;
      }
}

// ---------------- GEMM2 (MFMA bf16x3): y += (h W2) * route_weight ----------------
__global__ __launch_bounds__(256, 2) void gemm2_kernel(
    const float* __restrict__ h, const float* __restrict__ w2,
    const int* __restrict__ atok, const float* __restrict__ aw,
    const int* __restrict__ tile_e, float* __restrict__ y,
    int hc0, int CH)
{
  __shared__ unsigned short sAh[4096], sAl[4096];   // 128x32
  __shared__ unsigned short sBh[2048], sBl[2048];   // 32k x 64n

  const int rt = blockIdx.x, ct = blockIdx.y;
  const int row0 = rt * BM;
  const int tid = threadIdx.x;
  const int lane = tid & 63;
  const int wv = tid >> 6, wr = wv >> 1, wc = wv & 1;
  const int e = tile_e[rt];

  // A staging (h rows, contiguous)
  const int c4 = tid & 7;
  const int srow = tid >> 3;
  const float* ax[4];
  int aadr[4];
#pragma unroll
  for (int i = 0; i < 4; ++i) {
    const int r = srow + 32 * i;
    ax[i] = h + (size_t)(row0 + r) * CH + c4 * 4;
    aadr[i] = fragoff(r, c4 * 4);
  }
  // B staging: w2 rows are n-contiguous; thread = (n = tid&63, k-quad = tid>>6 (+4))
  const int n = tid & 63;
  const int kq0 = tid >> 6;
  const float* W2p = w2 + ((size_t)e * HID + hc0) * DIM + (size_t)ct * BN + n;

  const f32x4 vz = {0.f, 0.f, 0.f, 0.f};
  f32x4 acc[4][2];
#pragma unroll
  for (int i = 0; i < 4; ++i)
#pragma unroll
    for (int j = 0; j < 2; ++j) acc[i][j] = vz;

  for (int kt = 0; kt < CH / BK; ++kt) {
    const int k0 = kt * BK;
    float4 av[4];
    float bv[2][4];
#pragma unroll
    for (int i = 0; i < 4; ++i) av[i] = *(const float4*)(ax[i] + k0);
#pragma unroll
    for (int i = 0; i < 2; ++i) {
      const int kq = kq0 + 4 * i;
#pragma unroll
      for (int q = 0; q < 4; ++q)
        bv[i][q] = W2p[(size_t)(k0 + kq * 4 + q) * DIM];
    }
    __syncthreads();
#pragma unroll
    for (int i = 0; i < 4; ++i) {
      ushort4 hi, lo;
      split2(av[i].x, hi.x, lo.x); split2(av[i].y, hi.y, lo.y);
      split2(av[i].z, hi.z, lo.z); split2(av[i].w, hi.w, lo.w);
      *(ushort4*)&sAh[aadr[i]] = hi;  *(ushort4*)&sAl[aadr[i]] = lo;
    }
#pragma unroll
    for (int i = 0; i < 2; ++i) {
      const int kq = kq0 + 4 * i;
      const int ba = ((n >> 4) << 9) + ((kq >> 1) << 7) + ((n & 15) << 3) + ((kq & 1) << 2);
      ushort4 hi, lo;
      split2(bv[i][0], hi.x, lo.x); split2(bv[i][1], hi.y, lo.y);
      split2(bv[i][2], hi.z, lo.z); split2(bv[i][3], hi.w, lo.w);
      *(ushort4*)&sBh[ba] = hi; *(ushort4*)&sBl[ba] = lo;
    }
    __syncthreads();

    bf16x8 ah[4], al[4], bh_[2], bl_[2];
#pragma unroll
    for (int ar = 0; ar < 4; ++ar) {
      const int rb = wr * 4 + ar;
      ah[ar] = *(const bf16x8*)&sAh[rb * 512 + lane * 8];
      al[ar] = *(const bf16x8*)&sAl[rb * 512 + lane * 8];
    }
#pragma unroll
    for (int bc = 0; bc < 2; ++bc) {
      const int cb = wc * 2 + bc;
      bh_[bc] = *(const bf16x8*)&sBh[cb * 512 + lane * 8];
      bl_[bc] = *(const bf16x8*)&sBl[cb * 512 + lane * 8];
    }
#pragma unroll
    for (int ar = 0; ar < 4; ++ar)
#pragma unroll
      for (int bc = 0; bc < 2; ++bc) {
        acc[ar][bc] = __builtin_amdgcn_mfma_f32_16x16x32_bf16(ah[ar], bh_[bc], acc[ar][bc], 0, 0, 0);
        acc[ar][bc] = __builtin_amdgcn_mfma_f32_16x16x32_bf16(ah[ar], bl_[bc], acc[ar][bc], 0, 0, 0);
        acc[ar][bc] = __builtin_amdgcn_mfma_f32_16x16x32_bf16(al[ar], bh_[bc], acc[ar][bc], 0, 0, 0);
      }
  }

#pragma unroll
  for (int ar = 0; ar < 4; ++ar)
#pragma unroll
    for (int r = 0; r < 4; ++r) {
      const int grow = row0 + wr * 64 + ar * 16 + (lane >> 4) * 4 + r;
      const int tok = atok[grow];
      if (tok >= 0) {
        const float wgt = aw[grow];
#pragma unroll
        for (int bc = 0; bc < 2; ++bc) {
          const int col = ct * BN + wc * 32 + bc * 16 + (lane & 15);
          atomicAdd(y + (size_t)tok * DIM + col, acc[ar][bc][r] * wgt);
        }
      }
    }
}

// ---------------- launch ----------------
extern "C" void kernel_launch(void* const* d_in, const int* in_sizes, int n_in,
                              void* d_out, int out_size, void* d_ws, size_t ws_size,
                              hipStream_t stream) {
  const float* x  = (const float*)d_in[0];
  const float* w1 = (const float*)d_in[1];
  const float* w2 = (const float*)d_in[2];
  const float* w3 = (const float*)d_in[3];
  const float* gw = (const float*)d_in[4];
  float* y = (float*)d_out;

  char* ws = (char*)d_ws;
  int*   counts  = (int*)(ws + WS_COUNTS);
  int*   cursors = (int*)(ws + WS_CURSORS);
  int*   offsets = (int*)(ws + WS_OFFSETS);
  int*   tile_e  = (int*)(ws + WS_TILE_E);
  int*   sel     = (int*)(ws + WS_SEL);
  float* wts     = (float*)(ws + WS_WTS);
  int*   atok    = (int*)(ws + WS_ATOK);
  float* aw      = (float*)(ws + WS_AW);
  float* h       = (float*)(ws + WS_H);

  // largest hidden-chunk (divisor of 2816, multiple of 64) fitting ws_size
  static const int chs[6] = {2816, 1408, 704, 256, 128, 64};
  int CH = 64;
  for (int i = 0; i < 6; ++i) {
    if ((size_t)WS_H + (size_t)CAP * (size_t)chs[i] * 4ull <= ws_size) { CH = chs[i]; break; }
  }

  hipMemsetAsync(counts, 0, 8 * sizeof(int), stream);
  hipMemsetAsync(atok, 0xFF, CAP * sizeof(int), stream);          // pad marker -1
  hipMemsetAsync(y, 0, (size_t)T_TOK * DIM * sizeof(float), stream);

  gate_kernel<<<T_TOK / 4, 256, 0, stream>>>(x, gw, sel, wts, counts);
  offsets_kernel<<<1, 64, 0, stream>>>(counts, offsets, cursors, tile_e);
  scatter_kernel<<<T_TOK / 256, 256, 0, stream>>>(sel, wts, cursors, atok, aw);

  for (int hc0 = 0; hc0 < HID; hc0 += CH) {
    gemm1_kernel<<<dim3(NRT, CH / BN), 256, 0, stream>>>(x, w1, w3, atok, tile_e, h, hc0, CH);
    gemm2_kernel<<<dim3(NRT, DIM / BN), 256, 0, stream>>>(h, w2, atok, aw, tile_e, y, hc0, CH);
  }
}